// Round 3
// baseline (236.315 us; speedup 1.0000x reference)
//
#include <hip/hip_runtime.h>

// NonSpikingInput: RK2 leaky integrator, closed form per step:
//   v' = 0.625*v + 0.075*i   (E_REST = I_BIAS = 0)
// Output = full history, (4096, 8192) fp32. Memory-bound: 268 MB -> ~43 us floor.
//
// R3: LDS round-trip, padded chunks, per-thread serial scan. 80.7 us, 2.5 TB/s.
// R4 FAILED-NEUTRAL: persistent pipeline + counted-waitcnt barriers. 81.8 us.
// R5 FAILED-NEUTRAL: 8 blocks/CU occupancy (20 KiB LDS). 79.1 us. BW pinned
//   at 2.5 TB/s both times -> the phase/barrier structure itself is the
//   limiter: waves rarely have VMEM in flight, LDS+barriers dominate lifetime.
// R6 change: remove LDS and barriers entirely. Wave-level affine prefix scan:
//   lane owns 8 consecutive steps; local contribution c (v-in=0) + per-lane
//   decay A^8; 4-step Hillis-Steele __shfl_up scan (multipliers A^8..A^64)
//   combines the 64 lanes exactly. Cross-segment carry = 64-step warm-up:
//   lanes 0..15 redundantly load the preceding 64 floats (L2-hit; neighbor
//   wave just fetched them) + 16-lane mini-scan. Every element has >=64-step
//   exact history (most 120+, more than R3-R5). Loads/stores perfectly
//   coalesced 2 KiB/wave contiguous, zero LDS, zero barriers -> each wave is
//   an independent streaming unit (the fillBuffer shape that hits 6.7 TB/s).

typedef float fx4 __attribute__((ext_vector_type(4)));

constexpr int TT  = 8192;   // time steps per row
constexpr int BLK = 256;    // threads per block (4 waves)
constexpr int SEG = 512;    // steps per wave-segment = 8 floats/lane
constexpr int WPB = BLK / 64;

__global__ __launch_bounds__(BLK, 8)
void neuron_scan(const float* __restrict__ in, float* __restrict__ out,
                 int nseg) {
    const float A   = 0.625f;
    const float Bc  = 0.075f;
    const float A4  = 0.152587890625f;           // A^4  (exact in fp32)
    const float A8  = 2.32830643653869629e-2f;   // A^8
    const float A16 = 5.42101086242752217e-4f;   // A^16
    const float A32 = 2.93873587705571877e-7f;   // A^32
    const float A64 = 8.63616855509444e-14f;     // A^64

    const int lane = threadIdx.x & 63;
    const int wid  = blockIdx.x * WPB + (threadIdx.x >> 6);
    const int nw   = gridDim.x * WPB;

    for (int s = wid; s < nseg; s += nw) {
        const int row = s >> 4;            // TT/SEG = 16 segments per row
        const int col = s & 15;
        const size_t base = (size_t)row * TT + (size_t)col * SEG;
        const fx4* src = (const fx4*)(in + base);

        // Coalesced load: wave covers [base, base+2048B) contiguous.
        fx4 x0 = src[2 * lane];
        fx4 x1 = src[2 * lane + 1];

        // Warm-up carry: scan the preceding 64 inputs from v=0 (A^64 ~ 9e-14
        // truncation, same policy as R3-R5). Lanes 0..15 hold 4 steps each.
        float vwarm = 0.0f;
        if (col > 0) {                     // uniform branch
            fx4 wx = {0.0f, 0.0f, 0.0f, 0.0f};
            if (lane < 16) wx = src[lane - 16];   // bytes [base-256, base)
            float cw;
            cw = Bc * wx.x;
            cw = fmaf(A, cw, Bc * wx.y);
            cw = fmaf(A, cw, Bc * wx.z);
            cw = fmaf(A, cw, Bc * wx.w);
            float u;
            u = __shfl_up(cw, 1); if (lane >= 1) cw = fmaf(A4,  u, cw);
            u = __shfl_up(cw, 2); if (lane >= 2) cw = fmaf(A8,  u, cw);
            u = __shfl_up(cw, 4); if (lane >= 4) cw = fmaf(A16, u, cw);
            u = __shfl_up(cw, 8); if (lane >= 8) cw = fmaf(A32, u, cw);
            vwarm = __shfl(cw, 15);        // inclusive over all 64 warm steps
        }

        // Local contribution of this lane's 8 steps, starting from v=0.
        float c;
        c = Bc * x0.x;
        c = fmaf(A, c, Bc * x0.y);
        c = fmaf(A, c, Bc * x0.z);
        c = fmaf(A, c, Bc * x0.w);
        c = fmaf(A, c, Bc * x1.x);
        c = fmaf(A, c, Bc * x1.y);
        c = fmaf(A, c, Bc * x1.z);
        c = fmaf(A, c, Bc * x1.w);
        // Fold the incoming carry into lane 0; the scan propagates it with
        // exact A^8k weights to lanes 1..15 (beyond that A^128 ~ 7e-27).
        if (lane == 0) c = fmaf(A8, vwarm, c);

        // Inclusive affine scan across lanes (per-lane decay is uniform A^8,
        // so composition reduces to weighted prefix sum).
        float u;
        u = __shfl_up(c, 1); if (lane >= 1) c = fmaf(A8,  u, c);
        u = __shfl_up(c, 2); if (lane >= 2) c = fmaf(A16, u, c);
        u = __shfl_up(c, 4); if (lane >= 4) c = fmaf(A32, u, c);
        u = __shfl_up(c, 8); if (lane >= 8) c = fmaf(A64, u, c);

        // v entering this lane's first step = inclusive value of lane-1.
        float venter = __shfl_up(c, 1);
        if (lane == 0) venter = vwarm;

        // Re-run the 8 steps exactly from venter, emitting the history.
        float v = venter;
        fx4 o0, o1;
        v = fmaf(A, v, Bc * x0.x); o0.x = v;
        v = fmaf(A, v, Bc * x0.y); o0.y = v;
        v = fmaf(A, v, Bc * x0.z); o0.z = v;
        v = fmaf(A, v, Bc * x0.w); o0.w = v;
        v = fmaf(A, v, Bc * x1.x); o1.x = v;
        v = fmaf(A, v, Bc * x1.y); o1.y = v;
        v = fmaf(A, v, Bc * x1.z); o1.z = v;
        v = fmaf(A, v, Bc * x1.w); o1.w = v;

        // Coalesced nontemporal store, mirror of the load.
        fx4* dst = (fx4*)(out + base);
        __builtin_nontemporal_store(o0, dst + 2 * lane);
        __builtin_nontemporal_store(o1, dst + 2 * lane + 1);
    }
}

extern "C" void kernel_launch(void* const* d_in, const int* in_sizes, int n_in,
                              void* d_out, int out_size, void* d_ws, size_t ws_size,
                              hipStream_t stream) {
    const float* in = (const float*)d_in[0];
    float* out = (float*)d_out;
    const int n_rows = in_sizes[0] / TT;          // 4096
    const int nseg = n_rows * (TT / SEG);         // 65536
    int blocks = 2048;                            // 8 blocks/CU, 8 segs/wave
    if (blocks * WPB > nseg) blocks = (nseg + WPB - 1) / WPB;
    neuron_scan<<<dim3(blocks), dim3(BLK), 0, stream>>>(in, out, nseg);
}